// Round 12
// baseline (128.970 us; speedup 1.0000x reference)
//
#include <hip/hip_runtime.h>
#include <math.h>

// Problem constants: B=1, T=256, D=512, M=64, H=8, HD=64, IN=256, HID=256
#define T_ 256
#define D_ 512
#define M_ 64
#define H_ 8
#define HD_ 64
#define HID_ 256

#define LOG2E 1.44269504088896340736f

// Workspace layout (floats):
//   y     @ 0        : 3*T*D    = 393216
//   abuf  @ 393216   : 16*T*HID = 1048576   (ai = [0..7], aj = [8..15], scaled by LOG2E)
//   pb    @ 1441792  : 32*T*T   = 2097152   (holds LOG2E * z-partials; hb aliases after attn)
//   o     @ 3538944  : T*D      = 131072
//   parts @ 3670016  : 4096
//   W4o   @ 3674112  : 262144
//   b4o   @ 3936256  : 512

// silu-accumulate on pre-scaled inputs: u = L*t; acc += w * u * sigmoid(t)
// (w is the RAW w2diff, so acc accumulates L * w * t * sigmoid(t))
#define SILU_ACC(acc, w, aa, bb) \
    { float u_ = (aa) + (bb); \
      float e_ = exp2f(-u_); \
      float sg_ = __builtin_amdgcn_rcpf(1.f + e_); \
      acc = fmaf((w) * u_, sg_, acc); }

#define GEMM_INNER \
    _Pragma("unroll") \
    for (int kk = 0; kk < 32; ++kk) { \
        float a0 = As[ty * 2 + 0][kk]; \
        float a1 = As[ty * 2 + 1][kk]; \
        float b0 = Bs[kk][tx * 2 + 0]; \
        float b1 = Bs[kk][tx * 2 + 1]; \
        a00 = fmaf(a0, b0, a00); a01 = fmaf(a0, b1, a01); \
        a10 = fmaf(a1, b0, a10); a11 = fmaf(a1, b1, a11); }

// ---------------------------------------------------------------------------
// k1: jobs 0..383   qkv tiles  y[z] = x @ {Wq,Wk,Wv}
//     jobs 384..639 W4o tiles  W4o = W4 @ Wo
//     jobs 640,641  b4o = b4 @ Wo
// Grid 642 x 256.
// ---------------------------------------------------------------------------
__global__ __launch_bounds__(256) void k1_kernel(
    const float* __restrict__ x,
    const float* __restrict__ Wq, const float* __restrict__ Wk,
    const float* __restrict__ Wv, const float* __restrict__ W4,
    const float* __restrict__ Wo, const float* __restrict__ b4,
    float* __restrict__ y, float* __restrict__ W4o, float* __restrict__ b4o)
{
    __shared__ __align__(16) float As[32][36];
    __shared__ __align__(16) float Bs[32][36];

    const int job = blockIdx.x;
    const int tid = threadIdx.x;
    const int tx = tid & 15, ty = tid >> 4;
    const int r4 = tid >> 3, c4 = tid & 7;

    if (job < 640) {
        const float* A;
        const float* B;
        float* C;
        int row0, col0;
        if (job < 384) {
            const int z = job >> 7, rem = job & 127;
            row0 = (rem >> 4) << 5; col0 = (rem & 15) << 5;
            A = x;
            B = (z == 0) ? Wq : (z == 1) ? Wk : Wv;
            C = y + (long)z * (T_ * D_);
        } else {
            const int idx = job - 384;                 // 0..255 (512x512 out)
            row0 = (idx >> 4) << 5; col0 = (idx & 15) << 5;
            A = W4; B = Wo; C = W4o;
        }
        float a00 = 0.f, a01 = 0.f, a10 = 0.f, a11 = 0.f;
        for (int k0 = 0; k0 < D_; k0 += 32) {
            *(float4*)&As[r4][c4 * 4] = *(const float4*)(A + (long)(row0 + r4) * D_ + k0 + c4 * 4);
            *(float4*)&Bs[r4][c4 * 4] = *(const float4*)(B + (long)(k0 + r4) * D_ + col0 + c4 * 4);
            __syncthreads();
            GEMM_INNER
            __syncthreads();
        }
        C[(long)(row0 + ty * 2 + 0) * D_ + col0 + tx * 2 + 0] = a00;
        C[(long)(row0 + ty * 2 + 0) * D_ + col0 + tx * 2 + 1] = a01;
        C[(long)(row0 + ty * 2 + 1) * D_ + col0 + tx * 2 + 0] = a10;
        C[(long)(row0 + ty * 2 + 1) * D_ + col0 + tx * 2 + 1] = a11;
    } else {
        // b4o[c] = sum_k b4[k] * Wo[k][c]
        const int c = (job - 640) * 256 + tid;
        float s = 0.f;
        for (int k = 0; k < D_; k += 4) {
            s = fmaf(b4[k + 0], Wo[(long)(k + 0) * D_ + c], s);
            s = fmaf(b4[k + 1], Wo[(long)(k + 1) * D_ + c], s);
            s = fmaf(b4[k + 2], Wo[(long)(k + 2) * D_ + c], s);
            s = fmaf(b4[k + 3], Wo[(long)(k + 3) * D_ + c], s);
        }
        b4o[c] = s;
    }
}

// ---------------------------------------------------------------------------
// aiaj: a_i / a_j with coords via K-concat (K = 64 + 64), grid (8, 8, 16).
// Output scaled by LOG2E (consumed by pairwise's exp2-based silu).
// ---------------------------------------------------------------------------
__global__ __launch_bounds__(256) void aiaj_kernel(
    const float* __restrict__ y, const float* __restrict__ coords,
    const float* __restrict__ W1, const float* __restrict__ b1,
    float* __restrict__ abuf)
{
    __shared__ __align__(16) float As[32][36];
    __shared__ __align__(16) float Bs[32][36];
    const int z = blockIdx.z;
    const int sel = z >> 3, h = z & 7;
    const float* Ay = y + (long)sel * (T_ * D_) + h * HD_;
    float* C = abuf + (long)z * (T_ * HID_);
    const int tid = threadIdx.x;
    const int tx = tid & 15, ty = tid >> 4;
    const int row0 = blockIdx.y * 32, col0 = blockIdx.x * 32;
    const int r4 = tid >> 3, c4 = tid & 7;
    float a00 = 0.f, a01 = 0.f, a10 = 0.f, a11 = 0.f;
    for (int k0 = 0; k0 < 128; k0 += 32) {
        if (k0 < 64) {
            *(float4*)&As[r4][c4 * 4] =
                *(const float4*)(Ay + (long)(row0 + r4) * D_ + k0 + c4 * 4);
            *(float4*)&Bs[r4][c4 * 4] =
                *(const float4*)(W1 + (long)(sel * 64 + k0 + r4) * HID_ + col0 + c4 * 4);
        } else {
            *(float4*)&As[r4][c4 * 4] =
                *(const float4*)(coords + (long)(row0 + r4) * M_ + (k0 - 64) + c4 * 4);
            *(float4*)&Bs[r4][c4 * 4] =
                *(const float4*)(W1 + (long)(128 + 64 * sel + k0 - 64 + r4) * HID_ + col0 + c4 * 4);
        }
        __syncthreads();
        GEMM_INNER
        __syncthreads();
    }
    const int c0 = col0 + tx * 2, r0 = row0 + ty * 2;
    float bb0 = (sel == 1) ? b1[c0 + 0] : 0.f;
    float bb1 = (sel == 1) ? b1[c0 + 1] : 0.f;
    C[(long)(r0 + 0) * HID_ + c0 + 0] = (a00 + bb0) * LOG2E;
    C[(long)(r0 + 0) * HID_ + c0 + 1] = (a01 + bb1) * LOG2E;
    C[(long)(r0 + 1) * HID_ + c0 + 0] = (a10 + bb0) * LOG2E;
    C[(long)(r0 + 1) * HID_ + c0 + 1] = (a11 + bb1) * LOG2E;
}

// ---------------------------------------------------------------------------
// pairwise: 32x32 tile, feature-split x4. Grid (8, 8, 32) = 2048 blocks.
// Inputs pre-scaled by LOG2E; w2d raw => pb = LOG2E * z-partial.
// ---------------------------------------------------------------------------
__global__ __launch_bounds__(256) void pairwise_kernel(
    const float* __restrict__ a_i, const float* __restrict__ a_j,
    const float* __restrict__ W2, float* __restrict__ pb)
{
    const int jt = blockIdx.x, it = blockIdx.y, hs = blockIdx.z;
    const int h = hs >> 2, fb = (hs & 3) * 64;
    const int t = threadIdx.x;
    __shared__ __align__(16) float ai_s[32][68];
    __shared__ __align__(16) float aj_s[32][68];
    __shared__ __align__(16) float w2d[64];
    if (t < 64) w2d[t] = W2[(fb + t) * 2 + 0] - W2[(fb + t) * 2 + 1];
    const float* aib = a_i + ((long)h * T_ + it * 32) * HID_ + fb;
    const float* ajb = a_j + ((long)h * T_ + jt * 32) * HID_ + fb;
    #pragma unroll
    for (int l = 0; l < 2; ++l) {
        int idx = t + l * 256;
        int r = idx >> 4, c4 = idx & 15;
        *(float4*)&ai_s[r][c4 * 4] = *(const float4*)(aib + (long)r * HID_ + c4 * 4);
        *(float4*)&aj_s[r][c4 * 4] = *(const float4*)(ajb + (long)r * HID_ + c4 * 4);
    }
    __syncthreads();
    const int ty = t >> 4, tx = t & 15;
    float s00 = 0.f, s01 = 0.f, s10 = 0.f, s11 = 0.f;
    #pragma unroll 4
    for (int f4 = 0; f4 < 16; ++f4) {
        float4 a0 = *(const float4*)&ai_s[ty][f4 * 4];
        float4 a1 = *(const float4*)&ai_s[ty + 16][f4 * 4];
        float4 c0 = *(const float4*)&aj_s[tx][f4 * 4];
        float4 c1 = *(const float4*)&aj_s[tx + 16][f4 * 4];
        float4 w  = *(const float4*)&w2d[f4 * 4];
        SILU_ACC(s00, w.x, a0.x, c0.x); SILU_ACC(s01, w.x, a0.x, c1.x);
        SILU_ACC(s10, w.x, a1.x, c0.x); SILU_ACC(s11, w.x, a1.x, c1.x);
        SILU_ACC(s00, w.y, a0.y, c0.y); SILU_ACC(s01, w.y, a0.y, c1.y);
        SILU_ACC(s10, w.y, a1.y, c0.y); SILU_ACC(s11, w.y, a1.y, c1.y);
        SILU_ACC(s00, w.z, a0.z, c0.z); SILU_ACC(s01, w.z, a0.z, c1.z);
        SILU_ACC(s10, w.z, a1.z, c0.z); SILU_ACC(s11, w.z, a1.z, c1.z);
        SILU_ACC(s00, w.w, a0.w, c0.w); SILU_ACC(s01, w.w, a0.w, c1.w);
        SILU_ACC(s10, w.w, a1.w, c0.w); SILU_ACC(s11, w.w, a1.w, c1.w);
    }
    const int gi0 = it * 32 + ty, gi1 = gi0 + 16;
    const int gj0 = jt * 32 + tx, gj1 = gj0 + 16;
    float* pbh = pb + (long)hs * (T_ * T_);
    pbh[(long)gi0 * T_ + gj0] = s00;
    pbh[(long)gi0 * T_ + gj1] = s01;
    pbh[(long)gi1 * T_ + gj0] = s10;
    pbh[(long)gi1 * T_ + gj1] = s11;
}

// ---------------------------------------------------------------------------
// attn: one block per row i (512 threads = 8 waves = 8 heads).
// pb holds LOG2E*z-partial; s' = sum + LOG2E*b2d; tanh via exp2 (no mul).
// ---------------------------------------------------------------------------
__global__ __launch_bounds__(512) void attn_kernel(
    const float* __restrict__ pb, const float* __restrict__ yv,
    const float* __restrict__ b2, float* __restrict__ o,
    float* __restrict__ parts)
{
    const int i = blockIdx.x, t = threadIdx.x;
    const int w = t >> 6, lane = t & 63;
    __shared__ float p[8][256];
    __shared__ float psc[8];
    const float b2dL = (b2[0] - b2[1]) * LOG2E;
    const float* pb0 = pb + ((long)(4 * w + 0) * T_ + i) * T_;
    const float* pb1 = pb + ((long)(4 * w + 1) * T_ + i) * T_;
    const float* pb2 = pb + ((long)(4 * w + 2) * T_ + i) * T_;
    const float* pb3 = pb + ((long)(4 * w + 3) * T_ + i) * T_;
    float sv[4];
    float mx = -1e30f, wsum = 0.f, asum = 0.f;
    #pragma unroll
    for (int r = 0; r < 4; ++r) {
        int j = lane + r * 64;
        float s = ((pb0[j] + pb1[j]) + (pb2[j] + pb3[j])) + b2dL;  // = LOG2E * s_orig
        float as = fabsf(s);
        float e = exp2f(-as);                                      // = exp(-|s_orig|)
        float tv = (1.f - e) * __builtin_amdgcn_rcpf(1.f + e);     // tanh(|s_orig|/2)
        float lk = (s < 0.f) ? -tv : tv;                           // tanh(s_orig/2)
        wsum += lk; asum += fabsf(lk);
        float sc = (j <= i) ? lk * 0.125f : -1e30f;
        sv[r] = sc; mx = fmaxf(mx, sc);
    }
    #pragma unroll
    for (int off = 32; off > 0; off >>= 1) mx = fmaxf(mx, __shfl_xor(mx, off));
    float sum = 0.f;
    #pragma unroll
    for (int r = 0; r < 4; ++r) {
        int j = lane + r * 64;
        float e = (j <= i) ? __expf(sv[r] - mx) : 0.f;
        p[w][j] = e; sum += e;
    }
    #pragma unroll
    for (int off = 32; off > 0; off >>= 1) {
        sum  += __shfl_xor(sum, off);
        wsum += __shfl_xor(wsum, off);
        asum += __shfl_xor(asum, off);
    }
    if (lane == 0) {
        psc[w] = __builtin_amdgcn_rcpf(sum);
        parts[((long)i * 8 + w) * 2 + 0] = wsum;
        parts[((long)i * 8 + w) * 2 + 1] = asum;
    }
    __syncthreads();
    const float pinv = psc[w];
    const float* vb = yv + t;
    float a0 = 0.f, a1 = 0.f, a2 = 0.f, a3 = 0.f;
    float a4 = 0.f, a5 = 0.f, a6 = 0.f, a7 = 0.f;
    int j = 0;
    for (; j + 7 <= i; j += 8) {
        a0 = fmaf(p[w][j + 0], vb[(long)(j + 0) * D_], a0);
        a1 = fmaf(p[w][j + 1], vb[(long)(j + 1) * D_], a1);
        a2 = fmaf(p[w][j + 2], vb[(long)(j + 2) * D_], a2);
        a3 = fmaf(p[w][j + 3], vb[(long)(j + 3) * D_], a3);
        a4 = fmaf(p[w][j + 4], vb[(long)(j + 4) * D_], a4);
        a5 = fmaf(p[w][j + 5], vb[(long)(j + 5) * D_], a5);
        a6 = fmaf(p[w][j + 6], vb[(long)(j + 6) * D_], a6);
        a7 = fmaf(p[w][j + 7], vb[(long)(j + 7) * D_], a7);
    }
    for (; j <= i; ++j) a0 = fmaf(p[w][j], vb[(long)j * D_], a0);
    o[(long)i * D_ + t] = (((a0 + a1) + (a2 + a3)) + ((a4 + a5) + (a6 + a7))) * pinv;
}

// ---------------------------------------------------------------------------
// epA: h[ks] = o @ W3 (K-split x4), grid (16, 8, 4)
// ---------------------------------------------------------------------------
__global__ __launch_bounds__(256) void epA_kernel(
    const float* __restrict__ o, const float* __restrict__ W3,
    float* __restrict__ hbuf)
{
    __shared__ __align__(16) float As[32][36];
    __shared__ __align__(16) float Bs[32][36];
    const int z = blockIdx.z;
    float* C = hbuf + (long)z * (T_ * D_);
    const int tid = threadIdx.x;
    const int tx = tid & 15, ty = tid >> 4;
    const int row0 = blockIdx.y * 32, col0 = blockIdx.x * 32;
    const int r4 = tid >> 3, c4 = tid & 7;
    float a00 = 0.f, a01 = 0.f, a10 = 0.f, a11 = 0.f;
    for (int k0 = z * 128; k0 < z * 128 + 128; k0 += 32) {
        *(float4*)&As[r4][c4 * 4] = *(const float4*)(o + (long)(row0 + r4) * D_ + k0 + c4 * 4);
        *(float4*)&Bs[r4][c4 * 4] = *(const float4*)(W3 + (long)(k0 + r4) * D_ + col0 + c4 * 4);
        __syncthreads();
        GEMM_INNER
        __syncthreads();
    }
    C[(long)(row0 + ty * 2 + 0) * D_ + col0 + tx * 2 + 0] = a00;
    C[(long)(row0 + ty * 2 + 0) * D_ + col0 + tx * 2 + 1] = a01;
    C[(long)(row0 + ty * 2 + 1) * D_ + col0 + tx * 2 + 0] = a10;
    C[(long)(row0 + ty * 2 + 1) * D_ + col0 + tx * 2 + 1] = a11;
}

// ---------------------------------------------------------------------------
// epF: out = silu(h0+h1+h2+h3 + b3) @ W4o + b4o  (+ tail reduce), grid (16, 8)
// ---------------------------------------------------------------------------
__global__ __launch_bounds__(256) void epF_kernel(
    const float* __restrict__ hbuf, const float* __restrict__ b3,
    const float* __restrict__ W4o, const float* __restrict__ b4o,
    float* __restrict__ out, const float* __restrict__ parts,
    float* __restrict__ tailo)
{
    __shared__ __align__(16) float As[32][36];
    __shared__ __align__(16) float Bs[32][36];
    const int tid = threadIdx.x;
    const int tx = tid & 15, ty = tid >> 4;
    const int row0 = blockIdx.y * 32, col0 = blockIdx.x * 32;
    const int r4 = tid >> 3, c4 = tid & 7;
    float a00 = 0.f, a01 = 0.f, a10 = 0.f, a11 = 0.f;
    for (int k0 = 0; k0 < D_; k0 += 32) {
        {
            long off = (long)(row0 + r4) * D_ + k0 + c4 * 4;
            float4 v0 = *(const float4*)(hbuf + off);
            float4 v1 = *(const float4*)(hbuf + 131072 + off);
            float4 v2 = *(const float4*)(hbuf + 262144 + off);
            float4 v3 = *(const float4*)(hbuf + 393216 + off);
            float4 bb = *(const float4*)(b3 + k0 + c4 * 4);
            float4 g;
            g.x = ((v0.x + v1.x) + (v2.x + v3.x)) + bb.x;
            g.y = ((v0.y + v1.y) + (v2.y + v3.y)) + bb.y;
            g.z = ((v0.z + v1.z) + (v2.z + v3.z)) + bb.z;
            g.w = ((v0.w + v1.w) + (v2.w + v3.w)) + bb.w;
            g.x = g.x * __builtin_amdgcn_rcpf(1.f + __expf(-g.x));
            g.y = g.y * __builtin_amdgcn_rcpf(1.f + __expf(-g.y));
            g.z = g.z * __builtin_amdgcn_rcpf(1.f + __expf(-g.z));
            g.w = g.w * __builtin_amdgcn_rcpf(1.f + __expf(-g.w));
            *(float4*)&As[r4][c4 * 4] = g;
        }
        *(float4*)&Bs[r4][c4 * 4] = *(const float4*)(W4o + (long)(k0 + r4) * D_ + col0 + c4 * 4);
        __syncthreads();
        GEMM_INNER
        __syncthreads();
    }
    const int c0 = col0 + tx * 2;
    out[(long)(row0 + ty * 2 + 0) * D_ + c0 + 0] = a00 + b4o[c0 + 0];
    out[(long)(row0 + ty * 2 + 0) * D_ + c0 + 1] = a01 + b4o[c0 + 1];
    out[(long)(row0 + ty * 2 + 1) * D_ + c0 + 0] = a10 + b4o[c0 + 0];
    out[(long)(row0 + ty * 2 + 1) * D_ + c0 + 1] = a11 + b4o[c0 + 1];

    if (blockIdx.x == 0 && blockIdx.y == 0 && tid < 64) {
        const int lane = tid;
        if (lane < 8) {
            float wsum = 0.f;
            for (int i = 0; i < 256; ++i) wsum += parts[((long)i * 8 + lane) * 2 + 0];
            tailo[lane] = wsum;
        }
        float a = 0.f;
        for (int idx = lane; idx < 2048; idx += 64) a += parts[(long)idx * 2 + 1];
        #pragma unroll
        for (int off = 32; off > 0; off >>= 1) a += __shfl_xor(a, off);
        if (lane == 0) tailo[8] = a / (float)(H_ * T_ * T_);
    }
}

// ---------------------------------------------------------------------------
extern "C" void kernel_launch(void* const* d_in, const int* in_sizes, int n_in,
                              void* d_out, int out_size, void* d_ws, size_t ws_size,
                              hipStream_t stream)
{
    const float* x      = (const float*)d_in[0];
    const float* coords = (const float*)d_in[1];
    const float* Wq     = (const float*)d_in[2];
    const float* Wk     = (const float*)d_in[3];
    const float* Wv     = (const float*)d_in[4];
    const float* Wo     = (const float*)d_in[5];
    const float* W1     = (const float*)d_in[6];
    const float* b1     = (const float*)d_in[7];
    const float* W2     = (const float*)d_in[8];
    const float* b2     = (const float*)d_in[9];
    const float* W3     = (const float*)d_in[10];
    const float* b3     = (const float*)d_in[11];
    const float* W4     = (const float*)d_in[12];
    const float* b4     = (const float*)d_in[13];
    float* out = (float*)d_out;

    float* ws = (float*)d_ws;
    float* y     = ws;                    // 3 * 256*512
    float* ai    = ws + 393216;           // abuf: ai [0..7], aj [8..15] (xLOG2E)
    float* aj    = ws + 917504;
    float* pb    = ws + 1441792;          // 32*T*T ; hb[4] aliases pb
    float* o     = ws + 3538944;          // 256*512
    float* parts = ws + 3670016;          // 4096
    float* W4o   = ws + 3674112;          // 512*512
    float* b4o   = ws + 3936256;          // 512
    float* hb    = pb;                    // 4 slices of T*D

    // 1) qkv + W4o=W4@Wo + b4o=b4@Wo (one dispatch)
    k1_kernel<<<dim3(642), dim3(256), 0, stream>>>(x, Wq, Wk, Wv, W4, Wo, b4,
                                                   y, W4o, b4o);

    // 2) a_i / a_j (coords K-concat, b1 folded, xLOG2E)
    aiaj_kernel<<<dim3(8, 8, 16), dim3(256), 0, stream>>>(y, coords, W1, b1, ai);

    // 3) pairwise silu-MLP raw partials (feature-split 4x, exp2 silu)
    pairwise_kernel<<<dim3(8, 8, 32), dim3(256), 0, stream>>>(ai, aj, W2, pb);

    // 4) tanh -> causal softmax -> PV (+ row partials)
    attn_kernel<<<dim3(T_), dim3(512), 0, stream>>>(pb, y + 2 * (T_ * D_), b2, o, parts);

    // 5) epA: h = o @ W3 (K-split x4)
    epA_kernel<<<dim3(16, 8, 4), dim3(256), 0, stream>>>(o, W3, hb);

    // 6) epF: out = silu(sum h + b3) @ W4o + b4o (+ tail reduce)
    epF_kernel<<<dim3(16, 8), dim3(256), 0, stream>>>(hb, b3, W4o, b4o, out,
                                                      parts, out + 131072);
}

// Round 13
// 116.969 us; speedup vs baseline: 1.1026x; 1.1026x over previous
//
#include <hip/hip_runtime.h>
#include <math.h>

// Problem constants: B=1, T=256, D=512, M=64, H=8, HD=64, IN=256, HID=256
#define T_ 256
#define D_ 512
#define M_ 64
#define H_ 8
#define HD_ 64
#define HID_ 256

// Workspace layout (floats):
//   y     @ 0        : 3*T*D    = 393216
//   abuf  @ 393216   : 16*T*HID = 1048576   (ai = [0..7], aj = [8..15])
//   pb    @ 1441792  : 8*T*T    = 524288    (raw z-partials; hb[4] aliases after attn)
//   o     @ 3538944  : T*D      = 131072
//   parts @ 3670016  : 4096
//   W4o   @ 3674112  : 262144
//   b4o   @ 3936256  : 512

#define SILU_ACC(acc, w, aa, bb) \
    { float t_ = (aa) + (bb); \
      float sg_ = __builtin_amdgcn_rcpf(1.f + __expf(-t_)); \
      acc = fmaf((w) * t_, sg_, acc); }

#define GEMM_INNER \
    _Pragma("unroll") \
    for (int kk = 0; kk < 32; ++kk) { \
        float a0 = As[ty * 2 + 0][kk]; \
        float a1 = As[ty * 2 + 1][kk]; \
        float b0 = Bs[kk][tx * 2 + 0]; \
        float b1 = Bs[kk][tx * 2 + 1]; \
        a00 = fmaf(a0, b0, a00); a01 = fmaf(a0, b1, a01); \
        a10 = fmaf(a1, b0, a10); a11 = fmaf(a1, b1, a11); }

// ---------------------------------------------------------------------------
// k1: jobs 0..383   qkv tiles  y[z] = x @ {Wq,Wk,Wv}
//     jobs 384..639 W4o tiles  W4o = W4 @ Wo
//     jobs 640,641  b4o = b4 @ Wo
// Grid 642 x 256.
// ---------------------------------------------------------------------------
__global__ __launch_bounds__(256) void k1_kernel(
    const float* __restrict__ x,
    const float* __restrict__ Wq, const float* __restrict__ Wk,
    const float* __restrict__ Wv, const float* __restrict__ W4,
    const float* __restrict__ Wo, const float* __restrict__ b4,
    float* __restrict__ y, float* __restrict__ W4o, float* __restrict__ b4o)
{
    __shared__ __align__(16) float As[32][36];
    __shared__ __align__(16) float Bs[32][36];

    const int job = blockIdx.x;
    const int tid = threadIdx.x;
    const int tx = tid & 15, ty = tid >> 4;
    const int r4 = tid >> 3, c4 = tid & 7;

    if (job < 640) {
        const float* A;
        const float* B;
        float* C;
        int row0, col0;
        if (job < 384) {
            const int z = job >> 7, rem = job & 127;
            row0 = (rem >> 4) << 5; col0 = (rem & 15) << 5;
            A = x;
            B = (z == 0) ? Wq : (z == 1) ? Wk : Wv;
            C = y + (long)z * (T_ * D_);
        } else {
            const int idx = job - 384;                 // 0..255 (512x512 out)
            row0 = (idx >> 4) << 5; col0 = (idx & 15) << 5;
            A = W4; B = Wo; C = W4o;
        }
        float a00 = 0.f, a01 = 0.f, a10 = 0.f, a11 = 0.f;
        for (int k0 = 0; k0 < D_; k0 += 32) {
            *(float4*)&As[r4][c4 * 4] = *(const float4*)(A + (long)(row0 + r4) * D_ + k0 + c4 * 4);
            *(float4*)&Bs[r4][c4 * 4] = *(const float4*)(B + (long)(k0 + r4) * D_ + col0 + c4 * 4);
            __syncthreads();
            GEMM_INNER
            __syncthreads();
        }
        C[(long)(row0 + ty * 2 + 0) * D_ + col0 + tx * 2 + 0] = a00;
        C[(long)(row0 + ty * 2 + 0) * D_ + col0 + tx * 2 + 1] = a01;
        C[(long)(row0 + ty * 2 + 1) * D_ + col0 + tx * 2 + 0] = a10;
        C[(long)(row0 + ty * 2 + 1) * D_ + col0 + tx * 2 + 1] = a11;
    } else {
        // b4o[c] = sum_k b4[k] * Wo[k][c]
        const int c = (job - 640) * 256 + tid;
        float s = 0.f;
        for (int k = 0; k < D_; k += 4) {
            s = fmaf(b4[k + 0], Wo[(long)(k + 0) * D_ + c], s);
            s = fmaf(b4[k + 1], Wo[(long)(k + 1) * D_ + c], s);
            s = fmaf(b4[k + 2], Wo[(long)(k + 2) * D_ + c], s);
            s = fmaf(b4[k + 3], Wo[(long)(k + 3) * D_ + c], s);
        }
        b4o[c] = s;
    }
}

// ---------------------------------------------------------------------------
// aiaj: a_i / a_j with coords via K-concat (K = 64 + 64), grid (8, 8, 16).
// ---------------------------------------------------------------------------
__global__ __launch_bounds__(256) void aiaj_kernel(
    const float* __restrict__ y, const float* __restrict__ coords,
    const float* __restrict__ W1, const float* __restrict__ b1,
    float* __restrict__ abuf)
{
    __shared__ __align__(16) float As[32][36];
    __shared__ __align__(16) float Bs[32][36];
    const int z = blockIdx.z;
    const int sel = z >> 3, h = z & 7;
    const float* Ay = y + (long)sel * (T_ * D_) + h * HD_;
    float* C = abuf + (long)z * (T_ * HID_);
    const int tid = threadIdx.x;
    const int tx = tid & 15, ty = tid >> 4;
    const int row0 = blockIdx.y * 32, col0 = blockIdx.x * 32;
    const int r4 = tid >> 3, c4 = tid & 7;
    float a00 = 0.f, a01 = 0.f, a10 = 0.f, a11 = 0.f;
    for (int k0 = 0; k0 < 128; k0 += 32) {
        if (k0 < 64) {
            *(float4*)&As[r4][c4 * 4] =
                *(const float4*)(Ay + (long)(row0 + r4) * D_ + k0 + c4 * 4);
            *(float4*)&Bs[r4][c4 * 4] =
                *(const float4*)(W1 + (long)(sel * 64 + k0 + r4) * HID_ + col0 + c4 * 4);
        } else {
            *(float4*)&As[r4][c4 * 4] =
                *(const float4*)(coords + (long)(row0 + r4) * M_ + (k0 - 64) + c4 * 4);
            *(float4*)&Bs[r4][c4 * 4] =
                *(const float4*)(W1 + (long)(128 + 64 * sel + k0 - 64 + r4) * HID_ + col0 + c4 * 4);
        }
        __syncthreads();
        GEMM_INNER
        __syncthreads();
    }
    const int c0 = col0 + tx * 2, r0 = row0 + ty * 2;
    float bb0 = (sel == 1) ? b1[c0 + 0] : 0.f;
    float bb1 = (sel == 1) ? b1[c0 + 1] : 0.f;
    C[(long)(r0 + 0) * HID_ + c0 + 0] = a00 + bb0;
    C[(long)(r0 + 0) * HID_ + c0 + 1] = a01 + bb1;
    C[(long)(r0 + 1) * HID_ + c0 + 0] = a10 + bb0;
    C[(long)(r0 + 1) * HID_ + c0 + 1] = a11 + bb1;
}

// ---------------------------------------------------------------------------
// pairwise v6: monolithic 32x32 (i,j) tile, FULL 256 features per block
// (best-measured variant, R2: 42.5 us). Raw sums -> pb[h][i][j].
// Grid (8 jt, 8 it, 8 h) = 512 blocks x 256.
// ---------------------------------------------------------------------------
__global__ __launch_bounds__(256) void pairwise_kernel(
    const float* __restrict__ a_i, const float* __restrict__ a_j,
    const float* __restrict__ W2, float* __restrict__ pb)
{
    const int jt = blockIdx.x;
    const int it = blockIdx.y;
    const int h  = blockIdx.z;
    const int t = threadIdx.x;

    __shared__ __align__(16) float ai_s[32][260];
    __shared__ __align__(16) float aj_s[32][260];
    __shared__ __align__(16) float w2d[256];

    w2d[t] = W2[t * 2 + 0] - W2[t * 2 + 1];

    const float* aib = a_i + ((long)h * T_ + it * 32) * HID_;
    const float* ajb = a_j + ((long)h * T_ + jt * 32) * HID_;
    #pragma unroll
    for (int l = 0; l < 8; ++l) {
        int idx = t + l * 256;   // float4 id 0..2047
        int r = idx >> 6, c4 = idx & 63;
        *(float4*)&ai_s[r][c4 * 4] = *(const float4*)(aib + (long)r * HID_ + c4 * 4);
        *(float4*)&aj_s[r][c4 * 4] = *(const float4*)(ajb + (long)r * HID_ + c4 * 4);
    }
    __syncthreads();

    const int ty = t >> 4, tx = t & 15;
    float s00 = 0.f, s01 = 0.f, s10 = 0.f, s11 = 0.f;

    #pragma unroll 4
    for (int f4 = 0; f4 < 64; ++f4) {
        float4 a0 = *(const float4*)&ai_s[ty][f4 * 4];
        float4 a1 = *(const float4*)&ai_s[ty + 16][f4 * 4];
        float4 c0 = *(const float4*)&aj_s[tx][f4 * 4];
        float4 c1 = *(const float4*)&aj_s[tx + 16][f4 * 4];
        float4 w  = *(const float4*)&w2d[f4 * 4];
        SILU_ACC(s00, w.x, a0.x, c0.x); SILU_ACC(s01, w.x, a0.x, c1.x);
        SILU_ACC(s10, w.x, a1.x, c0.x); SILU_ACC(s11, w.x, a1.x, c1.x);
        SILU_ACC(s00, w.y, a0.y, c0.y); SILU_ACC(s01, w.y, a0.y, c1.y);
        SILU_ACC(s10, w.y, a1.y, c0.y); SILU_ACC(s11, w.y, a1.y, c1.y);
        SILU_ACC(s00, w.z, a0.z, c0.z); SILU_ACC(s01, w.z, a0.z, c1.z);
        SILU_ACC(s10, w.z, a1.z, c0.z); SILU_ACC(s11, w.z, a1.z, c1.z);
        SILU_ACC(s00, w.w, a0.w, c0.w); SILU_ACC(s01, w.w, a0.w, c1.w);
        SILU_ACC(s10, w.w, a1.w, c0.w); SILU_ACC(s11, w.w, a1.w, c1.w);
    }

    const int gi0 = it * 32 + ty, gi1 = gi0 + 16;
    const int gj0 = jt * 32 + tx, gj1 = gj0 + 16;
    float* pbh = pb + (long)h * (T_ * T_);
    pbh[(long)gi0 * T_ + gj0] = s00;
    pbh[(long)gi0 * T_ + gj1] = s01;
    pbh[(long)gi1 * T_ + gj0] = s10;
    pbh[(long)gi1 * T_ + gj1] = s11;
}

// ---------------------------------------------------------------------------
// attn: one block per row i (512 threads = 8 waves = 8 heads).
// Single-plane pb + b2d -> tanh -> causal softmax -> PV -> o row.
// ---------------------------------------------------------------------------
__global__ __launch_bounds__(512) void attn_kernel(
    const float* __restrict__ pb, const float* __restrict__ yv,
    const float* __restrict__ b2, float* __restrict__ o,
    float* __restrict__ parts)
{
    const int i = blockIdx.x, t = threadIdx.x;
    const int w = t >> 6, lane = t & 63;
    __shared__ float p[8][256];
    __shared__ float psc[8];
    const float b2d = b2[0] - b2[1];
    const float* pbh = pb + ((long)w * T_ + i) * T_;
    float sv[4];
    float mx = -1e30f, wsum = 0.f, asum = 0.f;
    #pragma unroll
    for (int r = 0; r < 4; ++r) {
        int j = lane + r * 64;
        float s = pbh[j] + b2d;
        float as = fabsf(s);
        float e = __expf(-as);
        float tv = (1.f - e) * __builtin_amdgcn_rcpf(1.f + e);   // tanh(|s|/2)
        float lk = (s < 0.f) ? -tv : tv;                          // tanh(s/2)
        wsum += lk; asum += fabsf(lk);
        float sc = (j <= i) ? lk * 0.125f : -1e30f;
        sv[r] = sc; mx = fmaxf(mx, sc);
    }
    #pragma unroll
    for (int off = 32; off > 0; off >>= 1) mx = fmaxf(mx, __shfl_xor(mx, off));
    float sum = 0.f;
    #pragma unroll
    for (int r = 0; r < 4; ++r) {
        int j = lane + r * 64;
        float e = (j <= i) ? __expf(sv[r] - mx) : 0.f;
        p[w][j] = e; sum += e;
    }
    #pragma unroll
    for (int off = 32; off > 0; off >>= 1) {
        sum  += __shfl_xor(sum, off);
        wsum += __shfl_xor(wsum, off);
        asum += __shfl_xor(asum, off);
    }
    if (lane == 0) {
        psc[w] = __builtin_amdgcn_rcpf(sum);
        parts[((long)i * 8 + w) * 2 + 0] = wsum;
        parts[((long)i * 8 + w) * 2 + 1] = asum;
    }
    __syncthreads();
    const float pinv = psc[w];
    const float* vb = yv + t;
    float a0 = 0.f, a1 = 0.f, a2 = 0.f, a3 = 0.f;
    float a4 = 0.f, a5 = 0.f, a6 = 0.f, a7 = 0.f;
    int j = 0;
    for (; j + 7 <= i; j += 8) {
        a0 = fmaf(p[w][j + 0], vb[(long)(j + 0) * D_], a0);
        a1 = fmaf(p[w][j + 1], vb[(long)(j + 1) * D_], a1);
        a2 = fmaf(p[w][j + 2], vb[(long)(j + 2) * D_], a2);
        a3 = fmaf(p[w][j + 3], vb[(long)(j + 3) * D_], a3);
        a4 = fmaf(p[w][j + 4], vb[(long)(j + 4) * D_], a4);
        a5 = fmaf(p[w][j + 5], vb[(long)(j + 5) * D_], a5);
        a6 = fmaf(p[w][j + 6], vb[(long)(j + 6) * D_], a6);
        a7 = fmaf(p[w][j + 7], vb[(long)(j + 7) * D_], a7);
    }
    for (; j <= i; ++j) a0 = fmaf(p[w][j], vb[(long)j * D_], a0);
    o[(long)i * D_ + t] = (((a0 + a1) + (a2 + a3)) + ((a4 + a5) + (a6 + a7))) * pinv;
}

// ---------------------------------------------------------------------------
// epA: h[ks] = o @ W3 (K-split x4), grid (16, 8, 4)
// ---------------------------------------------------------------------------
__global__ __launch_bounds__(256) void epA_kernel(
    const float* __restrict__ o, const float* __restrict__ W3,
    float* __restrict__ hbuf)
{
    __shared__ __align__(16) float As[32][36];
    __shared__ __align__(16) float Bs[32][36];
    const int z = blockIdx.z;
    float* C = hbuf + (long)z * (T_ * D_);
    const int tid = threadIdx.x;
    const int tx = tid & 15, ty = tid >> 4;
    const int row0 = blockIdx.y * 32, col0 = blockIdx.x * 32;
    const int r4 = tid >> 3, c4 = tid & 7;
    float a00 = 0.f, a01 = 0.f, a10 = 0.f, a11 = 0.f;
    for (int k0 = z * 128; k0 < z * 128 + 128; k0 += 32) {
        *(float4*)&As[r4][c4 * 4] = *(const float4*)(o + (long)(row0 + r4) * D_ + k0 + c4 * 4);
        *(float4*)&Bs[r4][c4 * 4] = *(const float4*)(W3 + (long)(k0 + r4) * D_ + col0 + c4 * 4);
        __syncthreads();
        GEMM_INNER
        __syncthreads();
    }
    C[(long)(row0 + ty * 2 + 0) * D_ + col0 + tx * 2 + 0] = a00;
    C[(long)(row0 + ty * 2 + 0) * D_ + col0 + tx * 2 + 1] = a01;
    C[(long)(row0 + ty * 2 + 1) * D_ + col0 + tx * 2 + 0] = a10;
    C[(long)(row0 + ty * 2 + 1) * D_ + col0 + tx * 2 + 1] = a11;
}

// ---------------------------------------------------------------------------
// epF: out = silu(h0+h1+h2+h3 + b3) @ W4o + b4o  (+ tail reduce), grid (16, 8)
// ---------------------------------------------------------------------------
__global__ __launch_bounds__(256) void epF_kernel(
    const float* __restrict__ hbuf, const float* __restrict__ b3,
    const float* __restrict__ W4o, const float* __restrict__ b4o,
    float* __restrict__ out, const float* __restrict__ parts,
    float* __restrict__ tailo)
{
    __shared__ __align__(16) float As[32][36];
    __shared__ __align__(16) float Bs[32][36];
    const int tid = threadIdx.x;
    const int tx = tid & 15, ty = tid >> 4;
    const int row0 = blockIdx.y * 32, col0 = blockIdx.x * 32;
    const int r4 = tid >> 3, c4 = tid & 7;
    float a00 = 0.f, a01 = 0.f, a10 = 0.f, a11 = 0.f;
    for (int k0 = 0; k0 < D_; k0 += 32) {
        {
            long off = (long)(row0 + r4) * D_ + k0 + c4 * 4;
            float4 v0 = *(const float4*)(hbuf + off);
            float4 v1 = *(const float4*)(hbuf + 131072 + off);
            float4 v2 = *(const float4*)(hbuf + 262144 + off);
            float4 v3 = *(const float4*)(hbuf + 393216 + off);
            float4 bb = *(const float4*)(b3 + k0 + c4 * 4);
            float4 g;
            g.x = ((v0.x + v1.x) + (v2.x + v3.x)) + bb.x;
            g.y = ((v0.y + v1.y) + (v2.y + v3.y)) + bb.y;
            g.z = ((v0.z + v1.z) + (v2.z + v3.z)) + bb.z;
            g.w = ((v0.w + v1.w) + (v2.w + v3.w)) + bb.w;
            g.x = g.x * __builtin_amdgcn_rcpf(1.f + __expf(-g.x));
            g.y = g.y * __builtin_amdgcn_rcpf(1.f + __expf(-g.y));
            g.z = g.z * __builtin_amdgcn_rcpf(1.f + __expf(-g.z));
            g.w = g.w * __builtin_amdgcn_rcpf(1.f + __expf(-g.w));
            *(float4*)&As[r4][c4 * 4] = g;
        }
        *(float4*)&Bs[r4][c4 * 4] = *(const float4*)(W4o + (long)(k0 + r4) * D_ + col0 + c4 * 4);
        __syncthreads();
        GEMM_INNER
        __syncthreads();
    }
    const int c0 = col0 + tx * 2;
    out[(long)(row0 + ty * 2 + 0) * D_ + c0 + 0] = a00 + b4o[c0 + 0];
    out[(long)(row0 + ty * 2 + 0) * D_ + c0 + 1] = a01 + b4o[c0 + 1];
    out[(long)(row0 + ty * 2 + 1) * D_ + c0 + 0] = a10 + b4o[c0 + 0];
    out[(long)(row0 + ty * 2 + 1) * D_ + c0 + 1] = a11 + b4o[c0 + 1];

    if (blockIdx.x == 0 && blockIdx.y == 0 && tid < 64) {
        const int lane = tid;
        if (lane < 8) {
            float wsum = 0.f;
            for (int i = 0; i < 256; ++i) wsum += parts[((long)i * 8 + lane) * 2 + 0];
            tailo[lane] = wsum;
        }
        float a = 0.f;
        for (int idx = lane; idx < 2048; idx += 64) a += parts[(long)idx * 2 + 1];
        #pragma unroll
        for (int off = 32; off > 0; off >>= 1) a += __shfl_xor(a, off);
        if (lane == 0) tailo[8] = a / (float)(H_ * T_ * T_);
    }
}

// ---------------------------------------------------------------------------
extern "C" void kernel_launch(void* const* d_in, const int* in_sizes, int n_in,
                              void* d_out, int out_size, void* d_ws, size_t ws_size,
                              hipStream_t stream)
{
    const float* x      = (const float*)d_in[0];
    const float* coords = (const float*)d_in[1];
    const float* Wq     = (const float*)d_in[2];
    const float* Wk     = (const float*)d_in[3];
    const float* Wv     = (const float*)d_in[4];
    const float* Wo     = (const float*)d_in[5];
    const float* W1     = (const float*)d_in[6];
    const float* b1     = (const float*)d_in[7];
    const float* W2     = (const float*)d_in[8];
    const float* b2     = (const float*)d_in[9];
    const float* W3     = (const float*)d_in[10];
    const float* b3     = (const float*)d_in[11];
    const float* W4     = (const float*)d_in[12];
    const float* b4     = (const float*)d_in[13];
    float* out = (float*)d_out;

    float* ws = (float*)d_ws;
    float* y     = ws;                    // 3 * 256*512
    float* ai    = ws + 393216;           // abuf: ai [0..7], aj [8..15]
    float* aj    = ws + 917504;
    float* pb    = ws + 1441792;          // 8*T*T ; hb[4] aliases pb
    float* o     = ws + 3538944;          // 256*512
    float* parts = ws + 3670016;          // 4096
    float* W4o   = ws + 3674112;          // 512*512
    float* b4o   = ws + 3936256;          // 512
    float* hb    = pb;                    // 4 slices of T*D = 524288 floats

    // 1) qkv + W4o=W4@Wo + b4o=b4@Wo (one dispatch)
    k1_kernel<<<dim3(642), dim3(256), 0, stream>>>(x, Wq, Wk, Wv, W4, Wo, b4,
                                                   y, W4o, b4o);

    // 2) a_i / a_j (coords K-concat, b1 folded)
    aiaj_kernel<<<dim3(8, 8, 16), dim3(256), 0, stream>>>(y, coords, W1, b1, ai);

    // 3) pairwise silu-MLP raw sums (monolithic 256-feature)
    pairwise_kernel<<<dim3(8, 8, 8), dim3(256), 0, stream>>>(ai, aj, W2, pb);

    // 4) tanh -> causal softmax -> PV (+ row partials)
    attn_kernel<<<dim3(T_), dim3(512), 0, stream>>>(pb, y + 2 * (T_ * D_), b2, o, parts);

    // 5) epA: h = o @ W3 (K-split x4)
    epA_kernel<<<dim3(16, 8, 4), dim3(256), 0, stream>>>(o, W3, hb);

    // 6) epF: out = silu(sum h + b3) @ W4o + b4o (+ tail reduce)
    epF_kernel<<<dim3(16, 8), dim3(256), 0, stream>>>(hb, b3, W4o, b4o, out,
                                                      parts, out + 131072);
}

// Round 14
// 113.872 us; speedup vs baseline: 1.1326x; 1.0272x over previous
//
#include <hip/hip_runtime.h>
#include <math.h>

// Problem constants: B=1, T=256, D=512, M=64, H=8, HD=64, IN=256, HID=256
#define T_ 256
#define D_ 512
#define M_ 64
#define H_ 8
#define HD_ 64
#define HID_ 256

#define LOG2E 1.44269504088896340736f

// Raw v_exp_f32 path: fold log2e into aiaj outputs, 1/log2e into w2d.
#if defined(__has_builtin)
#  if __has_builtin(__builtin_amdgcn_exp2f)
#    define RAW_EXP2 1
#  endif
#endif
#ifndef RAW_EXP2
#  define RAW_EXP2 0
#endif

#if RAW_EXP2
#  define SCALE_ LOG2E
#  define INV_SCALE_ (1.0f / LOG2E)
#  define EXPNEG(x) __builtin_amdgcn_exp2f(-(x))   // x is pre-scaled by LOG2E
#else
#  define SCALE_ 1.0f
#  define INV_SCALE_ 1.0f
#  define EXPNEG(x) __expf(-(x))
#endif

// Workspace layout (floats):
//   y     @ 0        : 3*T*D    = 393216
//   abuf  @ 393216   : 16*T*HID = 1048576   (ai = [0..7], aj = [8..15], xSCALE_)
//   pb    @ 1441792  : 16*T*T   = 1048576   (raw z-partials, 2 planes/head; hb aliases)
//   o     @ 3538944  : T*D      = 131072
//   parts @ 3670016  : 4096
//   W4o   @ 3674112  : 262144
//   b4o   @ 3936256  : 512

// silu-accumulate: u = SCALE_*t ; acc += (w/SCALE_) * u * sigmoid(t)
#define SILU_ACC(acc, w, aa, bb) \
    { float u_ = (aa) + (bb); \
      float e_ = EXPNEG(u_); \
      float sg_ = __builtin_amdgcn_rcpf(1.f + e_); \
      acc = fmaf((w) * u_, sg_, acc); }

#define GEMM_INNER \
    _Pragma("unroll") \
    for (int kk = 0; kk < 32; ++kk) { \
        float a0 = As[ty * 2 + 0][kk]; \
        float a1 = As[ty * 2 + 1][kk]; \
        float b0 = Bs[kk][tx * 2 + 0]; \
        float b1 = Bs[kk][tx * 2 + 1]; \
        a00 = fmaf(a0, b0, a00); a01 = fmaf(a0, b1, a01); \
        a10 = fmaf(a1, b0, a10); a11 = fmaf(a1, b1, a11); }

// ---------------------------------------------------------------------------
// k1: jobs 0..383   qkv tiles  y[z] = x @ {Wq,Wk,Wv}
//     jobs 384..639 W4o tiles  W4o = W4 @ Wo
//     jobs 640,641  b4o = b4 @ Wo
// Grid 642 x 256.
// ---------------------------------------------------------------------------
__global__ __launch_bounds__(256) void k1_kernel(
    const float* __restrict__ x,
    const float* __restrict__ Wq, const float* __restrict__ Wk,
    const float* __restrict__ Wv, const float* __restrict__ W4,
    const float* __restrict__ Wo, const float* __restrict__ b4,
    float* __restrict__ y, float* __restrict__ W4o, float* __restrict__ b4o)
{
    __shared__ __align__(16) float As[32][36];
    __shared__ __align__(16) float Bs[32][36];

    const int job = blockIdx.x;
    const int tid = threadIdx.x;
    const int tx = tid & 15, ty = tid >> 4;
    const int r4 = tid >> 3, c4 = tid & 7;

    if (job < 640) {
        const float* A;
        const float* B;
        float* C;
        int row0, col0;
        if (job < 384) {
            const int z = job >> 7, rem = job & 127;
            row0 = (rem >> 4) << 5; col0 = (rem & 15) << 5;
            A = x;
            B = (z == 0) ? Wq : (z == 1) ? Wk : Wv;
            C = y + (long)z * (T_ * D_);
        } else {
            const int idx = job - 384;                 // 0..255 (512x512 out)
            row0 = (idx >> 4) << 5; col0 = (idx & 15) << 5;
            A = W4; B = Wo; C = W4o;
        }
        float a00 = 0.f, a01 = 0.f, a10 = 0.f, a11 = 0.f;
        for (int k0 = 0; k0 < D_; k0 += 32) {
            *(float4*)&As[r4][c4 * 4] = *(const float4*)(A + (long)(row0 + r4) * D_ + k0 + c4 * 4);
            *(float4*)&Bs[r4][c4 * 4] = *(const float4*)(B + (long)(k0 + r4) * D_ + col0 + c4 * 4);
            __syncthreads();
            GEMM_INNER
            __syncthreads();
        }
        C[(long)(row0 + ty * 2 + 0) * D_ + col0 + tx * 2 + 0] = a00;
        C[(long)(row0 + ty * 2 + 0) * D_ + col0 + tx * 2 + 1] = a01;
        C[(long)(row0 + ty * 2 + 1) * D_ + col0 + tx * 2 + 0] = a10;
        C[(long)(row0 + ty * 2 + 1) * D_ + col0 + tx * 2 + 1] = a11;
    } else {
        // b4o[c] = sum_k b4[k] * Wo[k][c]
        const int c = (job - 640) * 256 + tid;
        float s = 0.f;
        for (int k = 0; k < D_; k += 4) {
            s = fmaf(b4[k + 0], Wo[(long)(k + 0) * D_ + c], s);
            s = fmaf(b4[k + 1], Wo[(long)(k + 1) * D_ + c], s);
            s = fmaf(b4[k + 2], Wo[(long)(k + 2) * D_ + c], s);
            s = fmaf(b4[k + 3], Wo[(long)(k + 3) * D_ + c], s);
        }
        b4o[c] = s;
    }
}

// ---------------------------------------------------------------------------
// aiaj: a_i / a_j with coords via K-concat (K = 64 + 64), grid (8, 8, 16).
// Outputs scaled by SCALE_ (for the raw-exp2 pairwise path).
// ---------------------------------------------------------------------------
__global__ __launch_bounds__(256) void aiaj_kernel(
    const float* __restrict__ y, const float* __restrict__ coords,
    const float* __restrict__ W1, const float* __restrict__ b1,
    float* __restrict__ abuf)
{
    __shared__ __align__(16) float As[32][36];
    __shared__ __align__(16) float Bs[32][36];
    const int z = blockIdx.z;
    const int sel = z >> 3, h = z & 7;
    const float* Ay = y + (long)sel * (T_ * D_) + h * HD_;
    float* C = abuf + (long)z * (T_ * HID_);
    const int tid = threadIdx.x;
    const int tx = tid & 15, ty = tid >> 4;
    const int row0 = blockIdx.y * 32, col0 = blockIdx.x * 32;
    const int r4 = tid >> 3, c4 = tid & 7;
    float a00 = 0.f, a01 = 0.f, a10 = 0.f, a11 = 0.f;
    for (int k0 = 0; k0 < 128; k0 += 32) {
        if (k0 < 64) {
            *(float4*)&As[r4][c4 * 4] =
                *(const float4*)(Ay + (long)(row0 + r4) * D_ + k0 + c4 * 4);
            *(float4*)&Bs[r4][c4 * 4] =
                *(const float4*)(W1 + (long)(sel * 64 + k0 + r4) * HID_ + col0 + c4 * 4);
        } else {
            *(float4*)&As[r4][c4 * 4] =
                *(const float4*)(coords + (long)(row0 + r4) * M_ + (k0 - 64) + c4 * 4);
            *(float4*)&Bs[r4][c4 * 4] =
                *(const float4*)(W1 + (long)(128 + 64 * sel + k0 - 64 + r4) * HID_ + col0 + c4 * 4);
        }
        __syncthreads();
        GEMM_INNER
        __syncthreads();
    }
    const int c0 = col0 + tx * 2, r0 = row0 + ty * 2;
    float bb0 = (sel == 1) ? b1[c0 + 0] : 0.f;
    float bb1 = (sel == 1) ? b1[c0 + 1] : 0.f;
    C[(long)(r0 + 0) * HID_ + c0 + 0] = (a00 + bb0) * SCALE_;
    C[(long)(r0 + 0) * HID_ + c0 + 1] = (a01 + bb1) * SCALE_;
    C[(long)(r0 + 1) * HID_ + c0 + 0] = (a10 + bb0) * SCALE_;
    C[(long)(r0 + 1) * HID_ + c0 + 1] = (a11 + bb1) * SCALE_;
}

// ---------------------------------------------------------------------------
// pairwise v7: 32x32 (i,j) tile, feature-split x2 (128 features per block).
// Grid (8 jt, 8 it, 16 hs) = 1024 blocks (exactly 4/CU; LDS 33.5 KB fits 4).
// 32-iteration inner loop keeps prologue amortization close to monolithic.
// Raw sums -> pb[hs][i][j], hs = h*2 + half.
// ---------------------------------------------------------------------------
__global__ __launch_bounds__(256) void pairwise_kernel(
    const float* __restrict__ a_i, const float* __restrict__ a_j,
    const float* __restrict__ W2, float* __restrict__ pb)
{
    const int jt = blockIdx.x;
    const int it = blockIdx.y;
    const int hs = blockIdx.z;
    const int h = hs >> 1, fb = (hs & 1) * 128;
    const int t = threadIdx.x;

    __shared__ __align__(16) float ai_s[32][132];
    __shared__ __align__(16) float aj_s[32][132];
    __shared__ __align__(16) float w2d[128];

    if (t < 128) w2d[t] = (W2[(fb + t) * 2 + 0] - W2[(fb + t) * 2 + 1]) * INV_SCALE_;

    const float* aib = a_i + ((long)h * T_ + it * 32) * HID_ + fb;
    const float* ajb = a_j + ((long)h * T_ + jt * 32) * HID_ + fb;
    #pragma unroll
    for (int l = 0; l < 4; ++l) {
        int idx = t + l * 256;          // float4 id 0..1023
        int r = idx >> 5, c4 = idx & 31;
        *(float4*)&ai_s[r][c4 * 4] = *(const float4*)(aib + (long)r * HID_ + c4 * 4);
        *(float4*)&aj_s[r][c4 * 4] = *(const float4*)(ajb + (long)r * HID_ + c4 * 4);
    }
    __syncthreads();

    const int ty = t >> 4, tx = t & 15;
    float s00 = 0.f, s01 = 0.f, s10 = 0.f, s11 = 0.f;

    #pragma unroll 4
    for (int f4 = 0; f4 < 32; ++f4) {
        float4 a0 = *(const float4*)&ai_s[ty][f4 * 4];
        float4 a1 = *(const float4*)&ai_s[ty + 16][f4 * 4];
        float4 c0 = *(const float4*)&aj_s[tx][f4 * 4];
        float4 c1 = *(const float4*)&aj_s[tx + 16][f4 * 4];
        float4 w  = *(const float4*)&w2d[f4 * 4];
        SILU_ACC(s00, w.x, a0.x, c0.x); SILU_ACC(s01, w.x, a0.x, c1.x);
        SILU_ACC(s10, w.x, a1.x, c0.x); SILU_ACC(s11, w.x, a1.x, c1.x);
        SILU_ACC(s00, w.y, a0.y, c0.y); SILU_ACC(s01, w.y, a0.y, c1.y);
        SILU_ACC(s10, w.y, a1.y, c0.y); SILU_ACC(s11, w.y, a1.y, c1.y);
        SILU_ACC(s00, w.z, a0.z, c0.z); SILU_ACC(s01, w.z, a0.z, c1.z);
        SILU_ACC(s10, w.z, a1.z, c0.z); SILU_ACC(s11, w.z, a1.z, c1.z);
        SILU_ACC(s00, w.w, a0.w, c0.w); SILU_ACC(s01, w.w, a0.w, c1.w);
        SILU_ACC(s10, w.w, a1.w, c0.w); SILU_ACC(s11, w.w, a1.w, c1.w);
    }

    const int gi0 = it * 32 + ty, gi1 = gi0 + 16;
    const int gj0 = jt * 32 + tx, gj1 = gj0 + 16;
    float* pbh = pb + (long)hs * (T_ * T_);
    pbh[(long)gi0 * T_ + gj0] = s00;
    pbh[(long)gi0 * T_ + gj1] = s01;
    pbh[(long)gi1 * T_ + gj0] = s10;
    pbh[(long)gi1 * T_ + gj1] = s11;
}

// ---------------------------------------------------------------------------
// attn: one block per row i (512 threads = 8 waves = 8 heads).
// Merge 2 pb planes + b2d -> tanh -> causal softmax -> PV -> o row.
// ---------------------------------------------------------------------------
__global__ __launch_bounds__(512) void attn_kernel(
    const float* __restrict__ pb, const float* __restrict__ yv,
    const float* __restrict__ b2, float* __restrict__ o,
    float* __restrict__ parts)
{
    const int i = blockIdx.x, t = threadIdx.x;
    const int w = t >> 6, lane = t & 63;
    __shared__ float p[8][256];
    __shared__ float psc[8];
    const float b2d = b2[0] - b2[1];
    const float* pb0 = pb + ((long)(2 * w + 0) * T_ + i) * T_;
    const float* pb1 = pb + ((long)(2 * w + 1) * T_ + i) * T_;
    float sv[4];
    float mx = -1e30f, wsum = 0.f, asum = 0.f;
    #pragma unroll
    for (int r = 0; r < 4; ++r) {
        int j = lane + r * 64;
        float s = (pb0[j] + pb1[j]) + b2d;
        float as = fabsf(s);
#if RAW_EXP2
        float e = __builtin_amdgcn_exp2f(-as * LOG2E);            // exp(-|s|)
#else
        float e = __expf(-as);
#endif
        float tv = (1.f - e) * __builtin_amdgcn_rcpf(1.f + e);    // tanh(|s|/2)
        float lk = (s < 0.f) ? -tv : tv;                           // tanh(s/2)
        wsum += lk; asum += fabsf(lk);
        float sc = (j <= i) ? lk * 0.125f : -1e30f;
        sv[r] = sc; mx = fmaxf(mx, sc);
    }
    #pragma unroll
    for (int off = 32; off > 0; off >>= 1) mx = fmaxf(mx, __shfl_xor(mx, off));
    float sum = 0.f;
    #pragma unroll
    for (int r = 0; r < 4; ++r) {
        int j = lane + r * 64;
        float e = (j <= i) ? __expf(sv[r] - mx) : 0.f;
        p[w][j] = e; sum += e;
    }
    #pragma unroll
    for (int off = 32; off > 0; off >>= 1) {
        sum  += __shfl_xor(sum, off);
        wsum += __shfl_xor(wsum, off);
        asum += __shfl_xor(asum, off);
    }
    if (lane == 0) {
        psc[w] = __builtin_amdgcn_rcpf(sum);
        parts[((long)i * 8 + w) * 2 + 0] = wsum;
        parts[((long)i * 8 + w) * 2 + 1] = asum;
    }
    __syncthreads();
    const float pinv = psc[w];
    const float* vb = yv + t;
    float a0 = 0.f, a1 = 0.f, a2 = 0.f, a3 = 0.f;
    float a4 = 0.f, a5 = 0.f, a6 = 0.f, a7 = 0.f;
    int j = 0;
    for (; j + 7 <= i; j += 8) {
        a0 = fmaf(p[w][j + 0], vb[(long)(j + 0) * D_], a0);
        a1 = fmaf(p[w][j + 1], vb[(long)(j + 1) * D_], a1);
        a2 = fmaf(p[w][j + 2], vb[(long)(j + 2) * D_], a2);
        a3 = fmaf(p[w][j + 3], vb[(long)(j + 3) * D_], a3);
        a4 = fmaf(p[w][j + 4], vb[(long)(j + 4) * D_], a4);
        a5 = fmaf(p[w][j + 5], vb[(long)(j + 5) * D_], a5);
        a6 = fmaf(p[w][j + 6], vb[(long)(j + 6) * D_], a6);
        a7 = fmaf(p[w][j + 7], vb[(long)(j + 7) * D_], a7);
    }
    for (; j <= i; ++j) a0 = fmaf(p[w][j], vb[(long)j * D_], a0);
    o[(long)i * D_ + t] = (((a0 + a1) + (a2 + a3)) + ((a4 + a5) + (a6 + a7))) * pinv;
}

// ---------------------------------------------------------------------------
// epA: h[ks] = o @ W3 (K-split x4), grid (16, 8, 4)
// ---------------------------------------------------------------------------
__global__ __launch_bounds__(256) void epA_kernel(
    const float* __restrict__ o, const float* __restrict__ W3,
    float* __restrict__ hbuf)
{
    __shared__ __align__(16) float As[32][36];
    __shared__ __align__(16) float Bs[32][36];
    const int z = blockIdx.z;
    float* C = hbuf + (long)z * (T_ * D_);
    const int tid = threadIdx.x;
    const int tx = tid & 15, ty = tid >> 4;
    const int row0 = blockIdx.y * 32, col0 = blockIdx.x * 32;
    const int r4 = tid >> 3, c4 = tid & 7;
    float a00 = 0.f, a01 = 0.f, a10 = 0.f, a11 = 0.f;
    for (int k0 = z * 128; k0 < z * 128 + 128; k0 += 32) {
        *(float4*)&As[r4][c4 * 4] = *(const float4*)(o + (long)(row0 + r4) * D_ + k0 + c4 * 4);
        *(float4*)&Bs[r4][c4 * 4] = *(const float4*)(W3 + (long)(k0 + r4) * D_ + col0 + c4 * 4);
        __syncthreads();
        GEMM_INNER
        __syncthreads();
    }
    C[(long)(row0 + ty * 2 + 0) * D_ + col0 + tx * 2 + 0] = a00;
    C[(long)(row0 + ty * 2 + 0) * D_ + col0 + tx * 2 + 1] = a01;
    C[(long)(row0 + ty * 2 + 1) * D_ + col0 + tx * 2 + 0] = a10;
    C[(long)(row0 + ty * 2 + 1) * D_ + col0 + tx * 2 + 1] = a11;
}

// ---------------------------------------------------------------------------
// epF: out = silu(h0+h1+h2+h3 + b3) @ W4o + b4o  (+ tail reduce), grid (16, 8)
// ---------------------------------------------------------------------------
__global__ __launch_bounds__(256) void epF_kernel(
    const float* __restrict__ hbuf, const float* __restrict__ b3,
    const float* __restrict__ W4o, const float* __restrict__ b4o,
    float* __restrict__ out, const float* __restrict__ parts,
    float* __restrict__ tailo)
{
    __shared__ __align__(16) float As[32][36];
    __shared__ __align__(16) float Bs[32][36];
    const int tid = threadIdx.x;
    const int tx = tid & 15, ty = tid >> 4;
    const int row0 = blockIdx.y * 32, col0 = blockIdx.x * 32;
    const int r4 = tid >> 3, c4 = tid & 7;
    float a00 = 0.f, a01 = 0.f, a10 = 0.f, a11 = 0.f;
    for (int k0 = 0; k0 < D_; k0 += 32) {
        {
            long off = (long)(row0 + r4) * D_ + k0 + c4 * 4;
            float4 v0 = *(const float4*)(hbuf + off);
            float4 v1 = *(const float4*)(hbuf + 131072 + off);
            float4 v2 = *(const float4*)(hbuf + 262144 + off);
            float4 v3 = *(const float4*)(hbuf + 393216 + off);
            float4 bb = *(const float4*)(b3 + k0 + c4 * 4);
            float4 g;
            g.x = ((v0.x + v1.x) + (v2.x + v3.x)) + bb.x;
            g.y = ((v0.y + v1.y) + (v2.y + v3.y)) + bb.y;
            g.z = ((v0.z + v1.z) + (v2.z + v3.z)) + bb.z;
            g.w = ((v0.w + v1.w) + (v2.w + v3.w)) + bb.w;
            g.x = g.x * __builtin_amdgcn_rcpf(1.f + __expf(-g.x));
            g.y = g.y * __builtin_amdgcn_rcpf(1.f + __expf(-g.y));
            g.z = g.z * __builtin_amdgcn_rcpf(1.f + __expf(-g.z));
            g.w = g.w * __builtin_amdgcn_rcpf(1.f + __expf(-g.w));
            *(float4*)&As[r4][c4 * 4] = g;
        }
        *(float4*)&Bs[r4][c4 * 4] = *(const float4*)(W4o + (long)(k0 + r4) * D_ + col0 + c4 * 4);
        __syncthreads();
        GEMM_INNER
        __syncthreads();
    }
    const int c0 = col0 + tx * 2;
    out[(long)(row0 + ty * 2 + 0) * D_ + c0 + 0] = a00 + b4o[c0 + 0];
    out[(long)(row0 + ty * 2 + 0) * D_ + c0 + 1] = a01 + b4o[c0 + 1];
    out[(long)(row0 + ty * 2 + 1) * D_ + c0 + 0] = a10 + b4o[c0 + 0];
    out[(long)(row0 + ty * 2 + 1) * D_ + c0 + 1] = a11 + b4o[c0 + 1];

    if (blockIdx.x == 0 && blockIdx.y == 0 && tid < 64) {
        const int lane = tid;
        if (lane < 8) {
            float wsum = 0.f;
            for (int i = 0; i < 256; ++i) wsum += parts[((long)i * 8 + lane) * 2 + 0];
            tailo[lane] = wsum;
        }
        float a = 0.f;
        for (int idx = lane; idx < 2048; idx += 64) a += parts[(long)idx * 2 + 1];
        #pragma unroll
        for (int off = 32; off > 0; off >>= 1) a += __shfl_xor(a, off);
        if (lane == 0) tailo[8] = a / (float)(H_ * T_ * T_);
    }
}

// ---------------------------------------------------------------------------
extern "C" void kernel_launch(void* const* d_in, const int* in_sizes, int n_in,
                              void* d_out, int out_size, void* d_ws, size_t ws_size,
                              hipStream_t stream)
{
    const float* x      = (const float*)d_in[0];
    const float* coords = (const float*)d_in[1];
    const float* Wq     = (const float*)d_in[2];
    const float* Wk     = (const float*)d_in[3];
    const float* Wv     = (const float*)d_in[4];
    const float* Wo     = (const float*)d_in[5];
    const float* W1     = (const float*)d_in[6];
    const float* b1     = (const float*)d_in[7];
    const float* W2     = (const float*)d_in[8];
    const float* b2     = (const float*)d_in[9];
    const float* W3     = (const float*)d_in[10];
    const float* b3     = (const float*)d_in[11];
    const float* W4     = (const float*)d_in[12];
    const float* b4     = (const float*)d_in[13];
    float* out = (float*)d_out;

    float* ws = (float*)d_ws;
    float* y     = ws;                    // 3 * 256*512
    float* ai    = ws + 393216;           // abuf: ai [0..7], aj [8..15] (xSCALE_)
    float* aj    = ws + 917504;
    float* pb    = ws + 1441792;          // 16*T*T ; hb[4] aliases pb
    float* o     = ws + 3538944;          // 256*512
    float* parts = ws + 3670016;          // 4096
    float* W4o   = ws + 3674112;          // 512*512
    float* b4o   = ws + 3936256;          // 512
    float* hb    = pb;                    // 4 slices of T*D = 524288 floats

    // 1) qkv + W4o=W4@Wo + b4o=b4@Wo (one dispatch)
    k1_kernel<<<dim3(642), dim3(256), 0, stream>>>(x, Wq, Wk, Wv, W4, Wo, b4,
                                                   y, W4o, b4o);

    // 2) a_i / a_j (coords K-concat, b1 folded, xSCALE_)
    aiaj_kernel<<<dim3(8, 8, 16), dim3(256), 0, stream>>>(y, coords, W1, b1, ai);

    // 3) pairwise silu-MLP raw sums (feature-split x2, raw exp2)
    pairwise_kernel<<<dim3(8, 8, 16), dim3(256), 0, stream>>>(ai, aj, W2, pb);

    // 4) tanh -> causal softmax -> PV (+ row partials)
    attn_kernel<<<dim3(T_), dim3(512), 0, stream>>>(pb, y + 2 * (T_ * D_), b2, o, parts);

    // 5) epA: h = o @ W3 (K-split x4)
    epA_kernel<<<dim3(16, 8, 4), dim3(256), 0, stream>>>(o, W3, hb);

    // 6) epF: out = silu(sum h + b3) @ W4o + b4o (+ tail reduce)
    epF_kernel<<<dim3(16, 8), dim3(256), 0, stream>>>(hb, b3, W4o, b4o, out,
                                                      parts, out + 131072);
}

// Round 15
// 109.998 us; speedup vs baseline: 1.1725x; 1.0352x over previous
//
#include <hip/hip_runtime.h>
#include <math.h>

// Problem constants: B=1, T=256, D=512, M=64, H=8, HD=64, IN=256, HID=256
#define T_ 256
#define D_ 512
#define M_ 64
#define H_ 8
#define HD_ 64
#define HID_ 256

// Workspace layout (floats):
//   y     @ 0        : 3*T*D    = 393216
//   abuf  @ 393216   : 16*T*HID = 1048576   (ai = [0..7], aj = [8..15], raw)
//   ebuf  @ 1441792  : 16*T*HID = 1048576   (exp(-ai) / exp(-aj))
//   pb    @ 2490368  : 16*T*T   = 1048576   (raw z-partials, 2 planes/head; hb aliases)
//   o     @ 3538944  : T*D      = 131072
//   parts @ 3670016  : 4096
//   W4o   @ 3674112  : 262144
//   b4o   @ 3936256  : 512

// silu-accumulate with factored exp: e = exp(-ai)*exp(-aj)  (no trans-exp!)
#define SILU_ACC(acc, w, aa, bb, ea, eb) \
    { float u_ = (aa) + (bb); \
      float e_ = (ea) * (eb); \
      float sg_ = __builtin_amdgcn_rcpf(1.f + e_); \
      acc = fmaf((w) * u_, sg_, acc); }

#define GEMM_INNER \
    _Pragma("unroll") \
    for (int kk = 0; kk < 32; ++kk) { \
        float a0 = As[ty * 2 + 0][kk]; \
        float a1 = As[ty * 2 + 1][kk]; \
        float b0 = Bs[kk][tx * 2 + 0]; \
        float b1 = Bs[kk][tx * 2 + 1]; \
        a00 = fmaf(a0, b0, a00); a01 = fmaf(a0, b1, a01); \
        a10 = fmaf(a1, b0, a10); a11 = fmaf(a1, b1, a11); }

// ---------------------------------------------------------------------------
// k1: jobs 0..383   qkv tiles  y[z] = x @ {Wq,Wk,Wv}
//     jobs 384..639 W4o tiles  W4o = W4 @ Wo
//     jobs 640,641  b4o = b4 @ Wo
// Grid 642 x 256.
// ---------------------------------------------------------------------------
__global__ __launch_bounds__(256) void k1_kernel(
    const float* __restrict__ x,
    const float* __restrict__ Wq, const float* __restrict__ Wk,
    const float* __restrict__ Wv, const float* __restrict__ W4,
    const float* __restrict__ Wo, const float* __restrict__ b4,
    float* __restrict__ y, float* __restrict__ W4o, float* __restrict__ b4o)
{
    __shared__ __align__(16) float As[32][36];
    __shared__ __align__(16) float Bs[32][36];

    const int job = blockIdx.x;
    const int tid = threadIdx.x;
    const int tx = tid & 15, ty = tid >> 4;
    const int r4 = tid >> 3, c4 = tid & 7;

    if (job < 640) {
        const float* A;
        const float* B;
        float* C;
        int row0, col0;
        if (job < 384) {
            const int z = job >> 7, rem = job & 127;
            row0 = (rem >> 4) << 5; col0 = (rem & 15) << 5;
            A = x;
            B = (z == 0) ? Wq : (z == 1) ? Wk : Wv;
            C = y + (long)z * (T_ * D_);
        } else {
            const int idx = job - 384;                 // 0..255 (512x512 out)
            row0 = (idx >> 4) << 5; col0 = (idx & 15) << 5;
            A = W4; B = Wo; C = W4o;
        }
        float a00 = 0.f, a01 = 0.f, a10 = 0.f, a11 = 0.f;
        for (int k0 = 0; k0 < D_; k0 += 32) {
            *(float4*)&As[r4][c4 * 4] = *(const float4*)(A + (long)(row0 + r4) * D_ + k0 + c4 * 4);
            *(float4*)&Bs[r4][c4 * 4] = *(const float4*)(B + (long)(k0 + r4) * D_ + col0 + c4 * 4);
            __syncthreads();
            GEMM_INNER
            __syncthreads();
        }
        C[(long)(row0 + ty * 2 + 0) * D_ + col0 + tx * 2 + 0] = a00;
        C[(long)(row0 + ty * 2 + 0) * D_ + col0 + tx * 2 + 1] = a01;
        C[(long)(row0 + ty * 2 + 1) * D_ + col0 + tx * 2 + 0] = a10;
        C[(long)(row0 + ty * 2 + 1) * D_ + col0 + tx * 2 + 1] = a11;
    } else {
        // b4o[c] = sum_k b4[k] * Wo[k][c]
        const int c = (job - 640) * 256 + tid;
        float s = 0.f;
        for (int k = 0; k < D_; k += 4) {
            s = fmaf(b4[k + 0], Wo[(long)(k + 0) * D_ + c], s);
            s = fmaf(b4[k + 1], Wo[(long)(k + 1) * D_ + c], s);
            s = fmaf(b4[k + 2], Wo[(long)(k + 2) * D_ + c], s);
            s = fmaf(b4[k + 3], Wo[(long)(k + 3) * D_ + c], s);
        }
        b4o[c] = s;
    }
}

// ---------------------------------------------------------------------------
// aiaj: a_i / a_j with coords via K-concat (K = 64 + 64), grid (8, 8, 16).
// Writes raw values AND exp(-value) (for pairwise's factored-exp silu).
// ---------------------------------------------------------------------------
__global__ __launch_bounds__(256) void aiaj_kernel(
    const float* __restrict__ y, const float* __restrict__ coords,
    const float* __restrict__ W1, const float* __restrict__ b1,
    float* __restrict__ abuf, float* __restrict__ ebuf)
{
    __shared__ __align__(16) float As[32][36];
    __shared__ __align__(16) float Bs[32][36];
    const int z = blockIdx.z;
    const int sel = z >> 3, h = z & 7;
    const float* Ay = y + (long)sel * (T_ * D_) + h * HD_;
    float* C = abuf + (long)z * (T_ * HID_);
    float* E = ebuf + (long)z * (T_ * HID_);
    const int tid = threadIdx.x;
    const int tx = tid & 15, ty = tid >> 4;
    const int row0 = blockIdx.y * 32, col0 = blockIdx.x * 32;
    const int r4 = tid >> 3, c4 = tid & 7;
    float a00 = 0.f, a01 = 0.f, a10 = 0.f, a11 = 0.f;
    for (int k0 = 0; k0 < 128; k0 += 32) {
        if (k0 < 64) {
            *(float4*)&As[r4][c4 * 4] =
                *(const float4*)(Ay + (long)(row0 + r4) * D_ + k0 + c4 * 4);
            *(float4*)&Bs[r4][c4 * 4] =
                *(const float4*)(W1 + (long)(sel * 64 + k0 + r4) * HID_ + col0 + c4 * 4);
        } else {
            *(float4*)&As[r4][c4 * 4] =
                *(const float4*)(coords + (long)(row0 + r4) * M_ + (k0 - 64) + c4 * 4);
            *(float4*)&Bs[r4][c4 * 4] =
                *(const float4*)(W1 + (long)(128 + 64 * sel + k0 - 64 + r4) * HID_ + col0 + c4 * 4);
        }
        __syncthreads();
        GEMM_INNER
        __syncthreads();
    }
    const int c0 = col0 + tx * 2, r0 = row0 + ty * 2;
    float bb0 = (sel == 1) ? b1[c0 + 0] : 0.f;
    float bb1 = (sel == 1) ? b1[c0 + 1] : 0.f;
    float v00 = a00 + bb0, v01 = a01 + bb1;
    float v10 = a10 + bb0, v11 = a11 + bb1;
    C[(long)(r0 + 0) * HID_ + c0 + 0] = v00;
    C[(long)(r0 + 0) * HID_ + c0 + 1] = v01;
    C[(long)(r0 + 1) * HID_ + c0 + 0] = v10;
    C[(long)(r0 + 1) * HID_ + c0 + 1] = v11;
    E[(long)(r0 + 0) * HID_ + c0 + 0] = __expf(-v00);
    E[(long)(r0 + 0) * HID_ + c0 + 1] = __expf(-v01);
    E[(long)(r0 + 1) * HID_ + c0 + 0] = __expf(-v10);
    E[(long)(r0 + 1) * HID_ + c0 + 1] = __expf(-v11);
}

// ---------------------------------------------------------------------------
// pairwise v8: 32x32 (i,j) tile, feature-split x2, FACTORED EXP (no trans-exp
// in inner loop: e = eai*eaj). Grid (8 jt, 8 it, 16 hs) = 1024 blocks.
// LDS 68 KB -> 2 blocks/CU. Raw sums -> pb[hs][i][j], hs = h*2 + half.
// ---------------------------------------------------------------------------
__global__ __launch_bounds__(256) void pairwise_kernel(
    const float* __restrict__ a_i, const float* __restrict__ a_j,
    const float* __restrict__ e_i, const float* __restrict__ e_j,
    const float* __restrict__ W2, float* __restrict__ pb)
{
    const int jt = blockIdx.x;
    const int it = blockIdx.y;
    const int hs = blockIdx.z;
    const int h = hs >> 1, fb = (hs & 1) * 128;
    const int t = threadIdx.x;

    __shared__ __align__(16) float ai_s[32][132];
    __shared__ __align__(16) float aj_s[32][132];
    __shared__ __align__(16) float ei_s[32][132];
    __shared__ __align__(16) float ej_s[32][132];
    __shared__ __align__(16) float w2d[128];

    if (t < 128) w2d[t] = W2[(fb + t) * 2 + 0] - W2[(fb + t) * 2 + 1];

    const long iof = ((long)h * T_ + it * 32) * HID_ + fb;
    const long jof = ((long)h * T_ + jt * 32) * HID_ + fb;
    #pragma unroll
    for (int l = 0; l < 4; ++l) {
        int idx = t + l * 256;          // float4 id 0..1023
        int r = idx >> 5, c4 = idx & 31;
        long ro = (long)r * HID_ + c4 * 4;
        *(float4*)&ai_s[r][c4 * 4] = *(const float4*)(a_i + iof + ro);
        *(float4*)&aj_s[r][c4 * 4] = *(const float4*)(a_j + jof + ro);
        *(float4*)&ei_s[r][c4 * 4] = *(const float4*)(e_i + iof + ro);
        *(float4*)&ej_s[r][c4 * 4] = *(const float4*)(e_j + jof + ro);
    }
    __syncthreads();

    const int ty = t >> 4, tx = t & 15;
    float s00 = 0.f, s01 = 0.f, s10 = 0.f, s11 = 0.f;

    #pragma unroll 4
    for (int f4 = 0; f4 < 32; ++f4) {
        float4 a0 = *(const float4*)&ai_s[ty][f4 * 4];
        float4 a1 = *(const float4*)&ai_s[ty + 16][f4 * 4];
        float4 c0 = *(const float4*)&aj_s[tx][f4 * 4];
        float4 c1 = *(const float4*)&aj_s[tx + 16][f4 * 4];
        float4 p0 = *(const float4*)&ei_s[ty][f4 * 4];
        float4 p1 = *(const float4*)&ei_s[ty + 16][f4 * 4];
        float4 q0 = *(const float4*)&ej_s[tx][f4 * 4];
        float4 q1 = *(const float4*)&ej_s[tx + 16][f4 * 4];
        float4 w  = *(const float4*)&w2d[f4 * 4];
        SILU_ACC(s00, w.x, a0.x, c0.x, p0.x, q0.x); SILU_ACC(s01, w.x, a0.x, c1.x, p0.x, q1.x);
        SILU_ACC(s10, w.x, a1.x, c0.x, p1.x, q0.x); SILU_ACC(s11, w.x, a1.x, c1.x, p1.x, q1.x);
        SILU_ACC(s00, w.y, a0.y, c0.y, p0.y, q0.y); SILU_ACC(s01, w.y, a0.y, c1.y, p0.y, q1.y);
        SILU_ACC(s10, w.y, a1.y, c0.y, p1.y, q0.y); SILU_ACC(s11, w.y, a1.y, c1.y, p1.y, q1.y);
        SILU_ACC(s00, w.z, a0.z, c0.z, p0.z, q0.z); SILU_ACC(s01, w.z, a0.z, c1.z, p0.z, q1.z);
        SILU_ACC(s10, w.z, a1.z, c0.z, p1.z, q0.z); SILU_ACC(s11, w.z, a1.z, c1.z, p1.z, q1.z);
        SILU_ACC(s00, w.w, a0.w, c0.w, p0.w, q0.w); SILU_ACC(s01, w.w, a0.w, c1.w, p0.w, q1.w);
        SILU_ACC(s10, w.w, a1.w, c0.w, p1.w, q0.w); SILU_ACC(s11, w.w, a1.w, c1.w, p1.w, q1.w);
    }

    const int gi0 = it * 32 + ty, gi1 = gi0 + 16;
    const int gj0 = jt * 32 + tx, gj1 = gj0 + 16;
    float* pbh = pb + (long)hs * (T_ * T_);
    pbh[(long)gi0 * T_ + gj0] = s00;
    pbh[(long)gi0 * T_ + gj1] = s01;
    pbh[(long)gi1 * T_ + gj0] = s10;
    pbh[(long)gi1 * T_ + gj1] = s11;
}

// ---------------------------------------------------------------------------
// attn: one block per row i (512 threads = 8 waves = 8 heads).
// Merge 2 pb planes + b2d -> tanh -> causal softmax -> PV -> o row.
// ---------------------------------------------------------------------------
__global__ __launch_bounds__(512) void attn_kernel(
    const float* __restrict__ pb, const float* __restrict__ yv,
    const float* __restrict__ b2, float* __restrict__ o,
    float* __restrict__ parts)
{
    const int i = blockIdx.x, t = threadIdx.x;
    const int w = t >> 6, lane = t & 63;
    __shared__ float p[8][256];
    __shared__ float psc[8];
    const float b2d = b2[0] - b2[1];
    const float* pb0 = pb + ((long)(2 * w + 0) * T_ + i) * T_;
    const float* pb1 = pb + ((long)(2 * w + 1) * T_ + i) * T_;
    float sv[4];
    float mx = -1e30f, wsum = 0.f, asum = 0.f;
    #pragma unroll
    for (int r = 0; r < 4; ++r) {
        int j = lane + r * 64;
        float s = (pb0[j] + pb1[j]) + b2d;
        float as = fabsf(s);
        float e = __expf(-as);
        float tv = (1.f - e) * __builtin_amdgcn_rcpf(1.f + e);    // tanh(|s|/2)
        float lk = (s < 0.f) ? -tv : tv;                           // tanh(s/2)
        wsum += lk; asum += fabsf(lk);
        float sc = (j <= i) ? lk * 0.125f : -1e30f;
        sv[r] = sc; mx = fmaxf(mx, sc);
    }
    #pragma unroll
    for (int off = 32; off > 0; off >>= 1) mx = fmaxf(mx, __shfl_xor(mx, off));
    float sum = 0.f;
    #pragma unroll
    for (int r = 0; r < 4; ++r) {
        int j = lane + r * 64;
        float e = (j <= i) ? __expf(sv[r] - mx) : 0.f;
        p[w][j] = e; sum += e;
    }
    #pragma unroll
    for (int off = 32; off > 0; off >>= 1) {
        sum  += __shfl_xor(sum, off);
        wsum += __shfl_xor(wsum, off);
        asum += __shfl_xor(asum, off);
    }
    if (lane == 0) {
        psc[w] = __builtin_amdgcn_rcpf(sum);
        parts[((long)i * 8 + w) * 2 + 0] = wsum;
        parts[((long)i * 8 + w) * 2 + 1] = asum;
    }
    __syncthreads();
    const float pinv = psc[w];
    const float* vb = yv + t;
    float a0 = 0.f, a1 = 0.f, a2 = 0.f, a3 = 0.f;
    float a4 = 0.f, a5 = 0.f, a6 = 0.f, a7 = 0.f;
    int j = 0;
    for (; j + 7 <= i; j += 8) {
        a0 = fmaf(p[w][j + 0], vb[(long)(j + 0) * D_], a0);
        a1 = fmaf(p[w][j + 1], vb[(long)(j + 1) * D_], a1);
        a2 = fmaf(p[w][j + 2], vb[(long)(j + 2) * D_], a2);
        a3 = fmaf(p[w][j + 3], vb[(long)(j + 3) * D_], a3);
        a4 = fmaf(p[w][j + 4], vb[(long)(j + 4) * D_], a4);
        a5 = fmaf(p[w][j + 5], vb[(long)(j + 5) * D_], a5);
        a6 = fmaf(p[w][j + 6], vb[(long)(j + 6) * D_], a6);
        a7 = fmaf(p[w][j + 7], vb[(long)(j + 7) * D_], a7);
    }
    for (; j <= i; ++j) a0 = fmaf(p[w][j], vb[(long)j * D_], a0);
    o[(long)i * D_ + t] = (((a0 + a1) + (a2 + a3)) + ((a4 + a5) + (a6 + a7))) * pinv;
}

// ---------------------------------------------------------------------------
// epA: h[ks] = o @ W3 (K-split x4), grid (16, 8, 4)
// ---------------------------------------------------------------------------
__global__ __launch_bounds__(256) void epA_kernel(
    const float* __restrict__ o, const float* __restrict__ W3,
    float* __restrict__ hbuf)
{
    __shared__ __align__(16) float As[32][36];
    __shared__ __align__(16) float Bs[32][36];
    const int z = blockIdx.z;
    float* C = hbuf + (long)z * (T_ * D_);
    const int tid = threadIdx.x;
    const int tx = tid & 15, ty = tid >> 4;
    const int row0 = blockIdx.y * 32, col0 = blockIdx.x * 32;
    const int r4 = tid >> 3, c4 = tid & 7;
    float a00 = 0.f, a01 = 0.f, a10 = 0.f, a11 = 0.f;
    for (int k0 = z * 128; k0 < z * 128 + 128; k0 += 32) {
        *(float4*)&As[r4][c4 * 4] = *(const float4*)(o + (long)(row0 + r4) * D_ + k0 + c4 * 4);
        *(float4*)&Bs[r4][c4 * 4] = *(const float4*)(W3 + (long)(k0 + r4) * D_ + col0 + c4 * 4);
        __syncthreads();
        GEMM_INNER
        __syncthreads();
    }
    C[(long)(row0 + ty * 2 + 0) * D_ + col0 + tx * 2 + 0] = a00;
    C[(long)(row0 + ty * 2 + 0) * D_ + col0 + tx * 2 + 1] = a01;
    C[(long)(row0 + ty * 2 + 1) * D_ + col0 + tx * 2 + 0] = a10;
    C[(long)(row0 + ty * 2 + 1) * D_ + col0 + tx * 2 + 1] = a11;
}

// ---------------------------------------------------------------------------
// epF: out = silu(h0+h1+h2+h3 + b3) @ W4o + b4o  (+ tail reduce), grid (16, 8)
// ---------------------------------------------------------------------------
__global__ __launch_bounds__(256) void epF_kernel(
    const float* __restrict__ hbuf, const float* __restrict__ b3,
    const float* __restrict__ W4o, const float* __restrict__ b4o,
    float* __restrict__ out, const float* __restrict__ parts,
    float* __restrict__ tailo)
{
    __shared__ __align__(16) float As[32][36];
    __shared__ __align__(16) float Bs[32][36];
    const int tid = threadIdx.x;
    const int tx = tid & 15, ty = tid >> 4;
    const int row0 = blockIdx.y * 32, col0 = blockIdx.x * 32;
    const int r4 = tid >> 3, c4 = tid & 7;
    float a00 = 0.f, a01 = 0.f, a10 = 0.f, a11 = 0.f;
    for (int k0 = 0; k0 < D_; k0 += 32) {
        {
            long off = (long)(row0 + r4) * D_ + k0 + c4 * 4;
            float4 v0 = *(const float4*)(hbuf + off);
            float4 v1 = *(const float4*)(hbuf + 131072 + off);
            float4 v2 = *(const float4*)(hbuf + 262144 + off);
            float4 v3 = *(const float4*)(hbuf + 393216 + off);
            float4 bb = *(const float4*)(b3 + k0 + c4 * 4);
            float4 g;
            g.x = ((v0.x + v1.x) + (v2.x + v3.x)) + bb.x;
            g.y = ((v0.y + v1.y) + (v2.y + v3.y)) + bb.y;
            g.z = ((v0.z + v1.z) + (v2.z + v3.z)) + bb.z;
            g.w = ((v0.w + v1.w) + (v2.w + v3.w)) + bb.w;
            g.x = g.x * __builtin_amdgcn_rcpf(1.f + __expf(-g.x));
            g.y = g.y * __builtin_amdgcn_rcpf(1.f + __expf(-g.y));
            g.z = g.z * __builtin_amdgcn_rcpf(1.f + __expf(-g.z));
            g.w = g.w * __builtin_amdgcn_rcpf(1.f + __expf(-g.w));
            *(float4*)&As[r4][c4 * 4] = g;
        }
        *(float4*)&Bs[r4][c4 * 4] = *(const float4*)(W4o + (long)(k0 + r4) * D_ + col0 + c4 * 4);
        __syncthreads();
        GEMM_INNER
        __syncthreads();
    }
    const int c0 = col0 + tx * 2;
    out[(long)(row0 + ty * 2 + 0) * D_ + c0 + 0] = a00 + b4o[c0 + 0];
    out[(long)(row0 + ty * 2 + 0) * D_ + c0 + 1] = a01 + b4o[c0 + 1];
    out[(long)(row0 + ty * 2 + 1) * D_ + c0 + 0] = a10 + b4o[c0 + 0];
    out[(long)(row0 + ty * 2 + 1) * D_ + c0 + 1] = a11 + b4o[c0 + 1];

    if (blockIdx.x == 0 && blockIdx.y == 0 && tid < 64) {
        const int lane = tid;
        if (lane < 8) {
            float wsum = 0.f;
            for (int i = 0; i < 256; ++i) wsum += parts[((long)i * 8 + lane) * 2 + 0];
            tailo[lane] = wsum;
        }
        float a = 0.f;
        for (int idx = lane; idx < 2048; idx += 64) a += parts[(long)idx * 2 + 1];
        #pragma unroll
        for (int off = 32; off > 0; off >>= 1) a += __shfl_xor(a, off);
        if (lane == 0) tailo[8] = a / (float)(H_ * T_ * T_);
    }
}

// ---------------------------------------------------------------------------
extern "C" void kernel_launch(void* const* d_in, const int* in_sizes, int n_in,
                              void* d_out, int out_size, void* d_ws, size_t ws_size,
                              hipStream_t stream)
{
    const float* x      = (const float*)d_in[0];
    const float* coords = (const float*)d_in[1];
    const float* Wq     = (const float*)d_in[2];
    const float* Wk     = (const float*)d_in[3];
    const float* Wv     = (const float*)d_in[4];
    const float* Wo     = (const float*)d_in[5];
    const float* W1     = (const float*)d_in[6];
    const float* b1     = (const float*)d_in[7];
    const float* W2     = (const float*)d_in[8];
    const float* b2     = (const float*)d_in[9];
    const float* W3     = (const float*)d_in[10];
    const float* b3     = (const float*)d_in[11];
    const float* W4     = (const float*)d_in[12];
    const float* b4     = (const float*)d_in[13];
    float* out = (float*)d_out;

    float* ws = (float*)d_ws;
    float* y     = ws;                    // 3 * 256*512
    float* ai    = ws + 393216;           // abuf: ai [0..7], aj [8..15]
    float* aj    = ws + 917504;
    float* ei    = ws + 1441792;          // ebuf: exp(-ai) [0..7], exp(-aj) [8..15]
    float* ej    = ws + 1966080;
    float* pb    = ws + 2490368;          // 16*T*T ; hb[4] aliases pb
    float* o     = ws + 3538944;          // 256*512
    float* parts = ws + 3670016;          // 4096
    float* W4o   = ws + 3674112;          // 512*512
    float* b4o   = ws + 3936256;          // 512
    float* hb    = pb;                    // 4 slices of T*D = 524288 floats

    // 1) qkv + W4o=W4@Wo + b4o=b4@Wo (one dispatch)
    k1_kernel<<<dim3(642), dim3(256), 0, stream>>>(x, Wq, Wk, Wv, W4, Wo, b4,
                                                   y, W4o, b4o);

    // 2) a_i / a_j (coords K-concat, b1 folded) + exp(-a) sidecar
    aiaj_kernel<<<dim3(8, 8, 16), dim3(256), 0, stream>>>(y, coords, W1, b1, ai, ei);

    // 3) pairwise silu-MLP raw sums (feature-split x2, factored exp)
    pairwise_kernel<<<dim3(8, 8, 16), dim3(256), 0, stream>>>(ai, aj, ei, ej, W2, pb);

    // 4) tanh -> causal softmax -> PV (+ row partials)
    attn_kernel<<<dim3(T_), dim3(512), 0, stream>>>(pb, y + 2 * (T_ * D_), b2, o, parts);

    // 5) epA: h = o @ W3 (K-split x4)
    epA_kernel<<<dim3(16, 8, 4), dim3(256), 0, stream>>>(o, W3, hb);

    // 6) epF: out = silu(sum h + b3) @ W4o + b4o (+ tail reduce)
    epF_kernel<<<dim3(16, 8), dim3(256), 0, stream>>>(hb, b3, W4o, b4o, out,
                                                      parts, out + 131072);
}